// Round 1
// baseline (1190.934 us; speedup 1.0000x reference)
//
#include <hip/hip_runtime.h>

#define NNODES 50000
#define NEDGES 400000
#define DIM    512

// ---------------- CSR build ----------------

__global__ void count_kernel(const int* __restrict__ dst, int* __restrict__ cnt) {
  int i = blockIdx.x * blockDim.x + threadIdx.x;
  if (i < NEDGES) atomicAdd(&cnt[dst[i]], 1);
}

// single-block exclusive scan of cnt -> offs (and a second copy into cursor)
__global__ void scan_kernel(const int* __restrict__ cnt, int* __restrict__ offs,
                            int* __restrict__ cursor) {
  __shared__ int waveSums[16];
  const int lane = threadIdx.x & 63;
  const int wid  = threadIdx.x >> 6;
  int carry = 0;
  for (int base = 0; base < NNODES; base += 1024) {
    int i = base + (int)threadIdx.x;
    int v = (i < NNODES) ? cnt[i] : 0;
    int s = v;
    #pragma unroll
    for (int d = 1; d < 64; d <<= 1) {
      int t = __shfl_up(s, d);
      if (lane >= d) s += t;
    }
    if (lane == 63) waveSums[wid] = s;
    __syncthreads();
    if (wid == 0 && lane < 16) {
      int ws = waveSums[lane];
      #pragma unroll
      for (int d = 1; d < 16; d <<= 1) {
        int t = __shfl_up(ws, d);
        if (lane >= d) ws += t;
      }
      waveSums[lane] = ws;  // inclusive scan of wave sums
    }
    __syncthreads();
    int wavePrefix = (wid == 0) ? 0 : waveSums[wid - 1];
    int excl = carry + wavePrefix + s - v;
    if (i < NNODES) { offs[i] = excl; cursor[i] = excl; }
    carry += waveSums[15];
    __syncthreads();  // protect waveSums before next chunk
  }
}

__global__ void fill_kernel(const int* __restrict__ src, const int* __restrict__ dst,
                            int* __restrict__ cursor, int* __restrict__ csr) {
  int i = blockIdx.x * blockDim.x + threadIdx.x;
  if (i < NEDGES) {
    int d = dst[i];
    int p = atomicAdd(&cursor[d], 1);
    csr[p] = src[i];
  }
}

// ---------------- mean aggregation (pull, one wave per node) ----------------

__global__ void aggregate_kernel(const float* __restrict__ x, const int* __restrict__ offs,
                                 const int* __restrict__ cnt, const int* __restrict__ csr,
                                 float* __restrict__ mean_agg) {
  int node = blockIdx.x * 4 + (int)(threadIdx.x >> 6);
  int lane = threadIdx.x & 63;
  if (node >= NNODES) return;
  int off = offs[node];
  int deg = cnt[node];
  float4 a0 = {0.f, 0.f, 0.f, 0.f};
  float4 a1 = {0.f, 0.f, 0.f, 0.f};
  for (int i = 0; i < deg; ++i) {
    int s = csr[off + i];  // wave-uniform
    const float4* row = (const float4*)(x + (size_t)s * DIM) + lane * 2;
    float4 v0 = row[0];
    float4 v1 = row[1];
    a0.x += v0.x; a0.y += v0.y; a0.z += v0.z; a0.w += v0.w;
    a1.x += v1.x; a1.y += v1.y; a1.z += v1.z; a1.w += v1.w;
  }
  float w = 1.0f / fmaxf((float)deg, 1.0f);
  a0.x *= w; a0.y *= w; a0.z *= w; a0.w *= w;
  a1.x *= w; a1.y *= w; a1.z *= w; a1.w *= w;
  float4* o = (float4*)(mean_agg + (size_t)node * DIM) + lane * 2;
  o[0] = a0;
  o[1] = a1;
}

// ---------------- fused GEMM: H = mean_agg @ Wl^T + x @ Wr^T ----------------
// (b_l mathematically cancels through BatchNorm mean subtraction; also zeros)

#define BM 128
#define BN 128
#define BK 32

__launch_bounds__(256, 2)
__global__ void gemm_kernel(const float* __restrict__ Agg, const float* __restrict__ X,
                            const float* __restrict__ Wl, const float* __restrict__ Wr,
                            float* __restrict__ H) {
  __shared__ float As[BK][BM];
  __shared__ float Bs[BK][BN];
  const int tid = threadIdx.x;
  const int tx = tid & 15;   // n
  const int ty = tid >> 4;   // m
  const int rowBase = blockIdx.x * BM;
  const int colBase = blockIdx.y * BN;

  float acc[8][8];
  #pragma unroll
  for (int i = 0; i < 8; ++i)
    #pragma unroll
    for (int j = 0; j < 8; ++j) acc[i][j] = 0.f;

  for (int t = 0; t < 32; ++t) {
    const float* Ap = (t < 16) ? Agg : X;
    const float* Bp = (t < 16) ? Wl : Wr;
    const int k0 = (t & 15) * BK;
    #pragma unroll
    for (int i = 0; i < 4; ++i) {
      int lin = tid + i * 256;        // 0..1023
      int r   = lin >> 3;             // 0..127
      int kq  = (lin & 7) * 4;        // 0..28
      int gm  = rowBase + r;
      float4 va = (gm < NNODES)
                    ? *(const float4*)(Ap + (size_t)gm * DIM + k0 + kq)
                    : make_float4(0.f, 0.f, 0.f, 0.f);
      As[kq + 0][r] = va.x; As[kq + 1][r] = va.y;
      As[kq + 2][r] = va.z; As[kq + 3][r] = va.w;
      float4 vb = *(const float4*)(Bp + (size_t)(colBase + r) * DIM + k0 + kq);
      Bs[kq + 0][r] = vb.x; Bs[kq + 1][r] = vb.y;
      Bs[kq + 2][r] = vb.z; Bs[kq + 3][r] = vb.w;
    }
    __syncthreads();
    #pragma unroll 8
    for (int k = 0; k < BK; ++k) {
      float a[8], b[8];
      *(float4*)&a[0] = *(const float4*)&As[k][ty * 8];
      *(float4*)&a[4] = *(const float4*)&As[k][ty * 8 + 4];
      *(float4*)&b[0] = *(const float4*)&Bs[k][tx * 8];
      *(float4*)&b[4] = *(const float4*)&Bs[k][tx * 8 + 4];
      #pragma unroll
      for (int i = 0; i < 8; ++i)
        #pragma unroll
        for (int j = 0; j < 8; ++j)
          acc[i][j] = fmaf(a[i], b[j], acc[i][j]);
    }
    __syncthreads();
  }

  #pragma unroll
  for (int i = 0; i < 8; ++i) {
    int gm = rowBase + ty * 8 + i;
    if (gm < NNODES) {
      float* Hp = H + (size_t)gm * DIM + colBase + tx * 8;
      *(float4*)Hp       = *(const float4*)&acc[i][0];
      *(float4*)(Hp + 4) = *(const float4*)&acc[i][4];
    }
  }
}

// ---------------- BatchNorm ----------------

__global__ void bn_stats(const float* __restrict__ H, float* __restrict__ sums,
                         float* __restrict__ sqs) {
  int c = (blockIdx.x & 1) * 256 + threadIdx.x;
  int r0 = blockIdx.x >> 1;  // 0..255
  float s = 0.f, q = 0.f;
  for (int r = r0; r < NNODES; r += 256) {
    float v = H[(size_t)r * DIM + c];
    s += v;
    q += v * v;
  }
  atomicAdd(&sums[c], s);
  atomicAdd(&sqs[c], q);
}

__global__ void bn_final(const float* __restrict__ sums, const float* __restrict__ sqs,
                         const float* __restrict__ gamma, const float* __restrict__ beta,
                         float* __restrict__ scale, float* __restrict__ shift) {
  int c = threadIdx.x;
  float mu  = sums[c] * (1.0f / (float)NNODES);
  float var = sqs[c] * (1.0f / (float)NNODES) - mu * mu;
  float inv = rsqrtf(var + 1e-5f);
  float sc = inv * gamma[c];
  scale[c] = sc;
  shift[c] = beta[c] - mu * sc;
}

__global__ void bn_apply(float* __restrict__ H, const float* __restrict__ X,
                         const float* __restrict__ scale, const float* __restrict__ shift) {
  const size_t total = (size_t)NNODES * (DIM / 4);
  for (size_t i = (size_t)blockIdx.x * blockDim.x + threadIdx.x; i < total;
       i += (size_t)gridDim.x * blockDim.x) {
    int c4 = ((int)(i & (DIM / 4 - 1))) * 4;
    float4 h = ((const float4*)H)[i];
    float4 xv = ((const float4*)X)[i];
    float4 r;
    r.x = fmaxf(fmaf(h.x, scale[c4 + 0], shift[c4 + 0]), 0.f) + xv.x;
    r.y = fmaxf(fmaf(h.y, scale[c4 + 1], shift[c4 + 1]), 0.f) + xv.y;
    r.z = fmaxf(fmaf(h.z, scale[c4 + 2], shift[c4 + 2]), 0.f) + xv.z;
    r.w = fmaxf(fmaf(h.w, scale[c4 + 3], shift[c4 + 3]), 0.f) + xv.w;
    ((float4*)H)[i] = r;
  }
}

// ---------------- launch ----------------

extern "C" void kernel_launch(void* const* d_in, const int* in_sizes, int n_in,
                              void* d_out, int out_size, void* d_ws, size_t ws_size,
                              hipStream_t stream) {
  (void)in_sizes; (void)n_in; (void)out_size; (void)ws_size;
  const float* x     = (const float*)d_in[0];
  const int*   ei    = (const int*)d_in[1];
  const float* Wl    = (const float*)d_in[2];
  // d_in[3] = b_l: cancels through BN mean subtraction (and is zeros) -> unused
  const float* Wr    = (const float*)d_in[4];
  const float* gamma = (const float*)d_in[5];
  const float* beta  = (const float*)d_in[6];
  float* H = (float*)d_out;  // h lives in d_out, finalized in place

  const int* src = ei;
  const int* dst = ei + NEDGES;

  char* w = (char*)d_ws;
  float* mean_agg = (float*)w;  w += (size_t)NNODES * DIM * 4;
  int* cnt    = (int*)w;        w += (size_t)NNODES * 4;
  int* offs   = (int*)w;        w += (size_t)NNODES * 4;
  int* cursor = (int*)w;        w += (size_t)NNODES * 4;
  int* csr    = (int*)w;        w += (size_t)NEDGES * 4;
  float* sums = (float*)w;      w += (size_t)DIM * 4;
  float* sqs  = (float*)w;      w += (size_t)DIM * 4;
  float* scale= (float*)w;      w += (size_t)DIM * 4;
  float* shift= (float*)w;      w += (size_t)DIM * 4;

  hipMemsetAsync(cnt, 0, (size_t)NNODES * 4, stream);
  hipMemsetAsync(sums, 0, (size_t)2 * DIM * 4, stream);  // sums+sqs contiguous

  count_kernel<<<(NEDGES + 255) / 256, 256, 0, stream>>>(dst, cnt);
  scan_kernel<<<1, 1024, 0, stream>>>(cnt, offs, cursor);
  fill_kernel<<<(NEDGES + 255) / 256, 256, 0, stream>>>(src, dst, cursor, csr);
  aggregate_kernel<<<(NNODES + 3) / 4, 256, 0, stream>>>(x, offs, cnt, csr, mean_agg);
  gemm_kernel<<<dim3((NNODES + BM - 1) / BM, DIM / BN), 256, 0, stream>>>(
      mean_agg, x, Wl, Wr, H);
  bn_stats<<<512, 256, 0, stream>>>(H, sums, sqs);
  bn_final<<<1, DIM, 0, stream>>>(sums, sqs, gamma, beta, scale, shift);
  bn_apply<<<2048, 256, 0, stream>>>(H, x, scale, shift);
}

// Round 3
// 688.725 us; speedup vs baseline: 1.7292x; 1.7292x over previous
//
#include <hip/hip_runtime.h>

#define NNODES 50000
#define NEDGES 400000
#define DIM    512

typedef float f32x4 __attribute__((ext_vector_type(4)));
typedef __bf16 bf16x8 __attribute__((ext_vector_type(8)));

// ---------------- helpers ----------------

// round-to-nearest-even fp32 -> bf16, returning the rounded value still as
// uint (hi half in bits 31:16)
__device__ __forceinline__ unsigned bf16_rne_bits(float f) {
  unsigned u = __float_as_uint(f);
  return u + 0x7FFF + ((u >> 16) & 1);  // hi16 = bf16 bits
}

__device__ __forceinline__ void async16(void* lds, const void* g) {
  __builtin_amdgcn_global_load_lds(
      (const __attribute__((address_space(1))) unsigned*)g,
      (__attribute__((address_space(3))) unsigned*)lds, 16, 0, 0);
}

// ---------------- CSR build ----------------

__global__ void count_kernel(const int* __restrict__ dst, int* __restrict__ cnt) {
  int i = blockIdx.x * blockDim.x + threadIdx.x;
  if (i < NEDGES) atomicAdd(&cnt[dst[i]], 1);
}

__global__ void scan_kernel(const int* __restrict__ cnt, int* __restrict__ offs,
                            int* __restrict__ cursor) {
  __shared__ int waveSums[16];
  const int lane = threadIdx.x & 63;
  const int wid  = threadIdx.x >> 6;
  int carry = 0;
  for (int base = 0; base < NNODES; base += 1024) {
    int i = base + (int)threadIdx.x;
    int v = (i < NNODES) ? cnt[i] : 0;
    int s = v;
    #pragma unroll
    for (int d = 1; d < 64; d <<= 1) {
      int t = __shfl_up(s, d);
      if (lane >= d) s += t;
    }
    if (lane == 63) waveSums[wid] = s;
    __syncthreads();
    if (wid == 0 && lane < 16) {
      int ws = waveSums[lane];
      #pragma unroll
      for (int d = 1; d < 16; d <<= 1) {
        int t = __shfl_up(ws, d);
        if (lane >= d) ws += t;
      }
      waveSums[lane] = ws;
    }
    __syncthreads();
    int wavePrefix = (wid == 0) ? 0 : waveSums[wid - 1];
    int excl = carry + wavePrefix + s - v;
    if (i < NNODES) { offs[i] = excl; cursor[i] = excl; }
    carry += waveSums[15];
    __syncthreads();
  }
}

__global__ void fill_kernel(const int* __restrict__ src, const int* __restrict__ dst,
                            int* __restrict__ cursor, int* __restrict__ csr) {
  int i = blockIdx.x * blockDim.x + threadIdx.x;
  if (i < NEDGES) {
    int d = dst[i];
    int p = atomicAdd(&cursor[d], 1);
    csr[p] = src[i];
  }
}

// ---------------- mean aggregation (pull, one wave per node) ----------------

__global__ void aggregate_kernel(const float* __restrict__ x, const int* __restrict__ offs,
                                 const int* __restrict__ cnt, const int* __restrict__ csr,
                                 float* __restrict__ mean_agg) {
  int node = blockIdx.x * 4 + (int)(threadIdx.x >> 6);
  int lane = threadIdx.x & 63;
  if (node >= NNODES) return;
  int off = offs[node];
  int deg = cnt[node];
  float4 a0 = {0.f, 0.f, 0.f, 0.f};
  float4 a1 = {0.f, 0.f, 0.f, 0.f};
  for (int i = 0; i < deg; ++i) {
    int s = csr[off + i];
    const float4* row = (const float4*)(x + (size_t)s * DIM) + lane * 2;
    float4 v0 = row[0];
    float4 v1 = row[1];
    a0.x += v0.x; a0.y += v0.y; a0.z += v0.z; a0.w += v0.w;
    a1.x += v1.x; a1.y += v1.y; a1.z += v1.z; a1.w += v1.w;
  }
  float w = 1.0f / fmaxf((float)deg, 1.0f);
  a0.x *= w; a0.y *= w; a0.z *= w; a0.w *= w;
  a1.x *= w; a1.y *= w; a1.z *= w; a1.w *= w;
  float4* o = (float4*)(mean_agg + (size_t)node * DIM) + lane * 2;
  o[0] = a0;
  o[1] = a1;
}

// ---------------- W -> bf16 hi/lo, concatenated [512][1024] ----------------
// Bcat[n][k] = (k<512 ? Wl[n][k] : Wr[n][k-512])

__global__ void convert_w_kernel(const float* __restrict__ Wl, const float* __restrict__ Wr,
                                 unsigned short* __restrict__ bhi,
                                 unsigned short* __restrict__ blo) {
  int t = blockIdx.x * blockDim.x + threadIdx.x;  // 65536 threads
  int n  = t >> 7;
  int k  = (t & 127) * 8;
  const float* s = (k < 512) ? (Wl + (size_t)n * 512 + k)
                             : (Wr + (size_t)n * 512 + (k - 512));
  float f[8];
  *(float4*)&f[0] = ((const float4*)s)[0];
  *(float4*)&f[4] = ((const float4*)s)[1];
  unsigned hi[8], lo[8];
  #pragma unroll
  for (int i = 0; i < 8; ++i) {
    unsigned r = bf16_rne_bits(f[i]);
    hi[i] = r;
    float hf = __uint_as_float(r & 0xFFFF0000u);
    lo[i] = bf16_rne_bits(f[i] - hf);
  }
  uint4 ph, pl;
  ph.x = (hi[0] >> 16) | (hi[1] & 0xFFFF0000u);
  ph.y = (hi[2] >> 16) | (hi[3] & 0xFFFF0000u);
  ph.z = (hi[4] >> 16) | (hi[5] & 0xFFFF0000u);
  ph.w = (hi[6] >> 16) | (hi[7] & 0xFFFF0000u);
  pl.x = (lo[0] >> 16) | (lo[1] & 0xFFFF0000u);
  pl.y = (lo[2] >> 16) | (lo[3] & 0xFFFF0000u);
  pl.z = (lo[4] >> 16) | (lo[5] & 0xFFFF0000u);
  pl.w = (lo[6] >> 16) | (lo[7] & 0xFFFF0000u);
  *(uint4*)(bhi + (size_t)n * 1024 + k) = ph;
  *(uint4*)(blo + (size_t)n * 1024 + k) = pl;
}

// ---------------- bf16x3 MFMA GEMM ----------------
// H[m][n] = sum_k Acat[m][k] * Bcat[n][k],  Acat = [mean_agg | x] (fp32, split
// to bf16 hi/lo in-kernel), Bcat = [Wl | Wr] (pre-split bf16 hi/lo).
// 128x128 tile, BK=64, 4 waves (2x2 of 64x64), 16x16x32 MFMA, XOR-swizzled LDS.

__launch_bounds__(256, 2)
__global__ void mfma_gemm(const float* __restrict__ Agg, const float* __restrict__ X,
                          const unsigned short* __restrict__ Bhi,
                          const unsigned short* __restrict__ Blo,
                          float* __restrict__ H) {
  __shared__ char lds[65536];
  char* As_hi = lds;            // [128 rows][128 B], swizzled
  char* As_lo = lds + 16384;
  char* Bs_hi = lds + 32768;
  char* Bs_lo = lds + 49152;

  const int tid  = (int)threadIdx.x;
  const int lane = tid & 63;
  const int w    = tid >> 6;
  const int colBase = blockIdx.x * 128;  // N (4 blocks) — fast dim: A-panel reuse
  const int rowBase = blockIdx.y * 128;  // M (391 blocks)

  const int q  = lane >> 4;
  const int r2 = lane & 15;
  const int wr = w >> 1, wc = w & 1;

  // B staging: pre-swizzled source chunk offset (bytes within row)
  const int schunk = (((tid & 7) ^ ((tid >> 3) & 7)) << 4);
  const int srowq  = tid >> 3;  // 0..31

  f32x4 zero = {0.f, 0.f, 0.f, 0.f};
  f32x4 acc[4][4];
  #pragma unroll
  for (int i = 0; i < 4; ++i)
    #pragma unroll
    for (int j = 0; j < 4; ++j) acc[i][j] = zero;

  for (int t = 0; t < 16; ++t) {
    const int kk = t * 64;  // bf16/f32 column in [0,1024)
    const float* Ap;
    int kf;
    if (t < 8) { Ap = Agg; kf = kk; } else { Ap = X; kf = kk - 512; }

    // --- A: fp32 global -> regs (8x float4 per thread) ---
    float4 av[8];
    #pragma unroll
    for (int c = 0; c < 8; ++c) {
      int idx16 = c * 256 + tid;        // 0..2047
      int row   = idx16 >> 4;           // 0..127
      int col16 = idx16 & 15;           // float4 within 64-float row
      int gr = rowBase + row;
      if (gr >= NNODES) gr = NNODES - 1;
      av[c] = *(const float4*)(Ap + (size_t)gr * 512 + kf + col16 * 4);
    }

    // --- B: async global->LDS, source pre-swizzled ---
    #pragma unroll
    for (int c = 0; c < 4; ++c) {
      int row = c * 32 + srowq;
      const char* gh = (const char*)Bhi + (size_t)(colBase + row) * 2048 + kk * 2 + schunk;
      const char* gl = (const char*)Blo + (size_t)(colBase + row) * 2048 + kk * 2 + schunk;
      async16(Bs_hi + c * 4096 + w * 1024, gh);
      async16(Bs_lo + c * 4096 + w * 1024, gl);
    }

    // --- A: split to hi/lo, swizzled ds_write ---
    #pragma unroll
    for (int c = 0; c < 8; ++c) {
      int idx16 = c * 256 + tid;
      int row   = idx16 >> 4;
      int col16 = idx16 & 15;
      int off = row * 128 + ((col16 * 8) ^ ((row & 7) << 4));
      float f0 = av[c].x, f1 = av[c].y, f2 = av[c].z, f3 = av[c].w;
      unsigned r0 = bf16_rne_bits(f0), r1 = bf16_rne_bits(f1);
      unsigned r2b = bf16_rne_bits(f2), r3 = bf16_rne_bits(f3);
      float l0 = f0 - __uint_as_float(r0 & 0xFFFF0000u);
      float l1 = f1 - __uint_as_float(r1 & 0xFFFF0000u);
      float l2 = f2 - __uint_as_float(r2b & 0xFFFF0000u);
      float l3 = f3 - __uint_as_float(r3 & 0xFFFF0000u);
      uint2 hw, lw;
      hw.x = (r0 >> 16) | (r1 & 0xFFFF0000u);
      hw.y = (r2b >> 16) | (r3 & 0xFFFF0000u);
      lw.x = (bf16_rne_bits(l0) >> 16) | (bf16_rne_bits(l1) & 0xFFFF0000u);
      lw.y = (bf16_rne_bits(l2) >> 16) | (bf16_rne_bits(l3) & 0xFFFF0000u);
      *(uint2*)(As_hi + off) = hw;
      *(uint2*)(As_lo + off) = lw;
    }

    __syncthreads();

    // --- compute: 2 k-substeps x 16 frags x 3 products ---
    #pragma unroll
    for (int ks = 0; ks < 2; ++ks) {
      const int cOff = (((ks * 4 + q) ^ (r2 & 7)) << 4);
      bf16x8 ah[4], al[4], bh[4], bl[4];
      #pragma unroll
      for (int i = 0; i < 4; ++i) {
        int arow = wr * 64 + i * 16 + r2;
        ah[i] = *(const bf16x8*)(As_hi + arow * 128 + cOff);
        al[i] = *(const bf16x8*)(As_lo + arow * 128 + cOff);
        int brow = wc * 64 + i * 16 + r2;
        bh[i] = *(const bf16x8*)(Bs_hi + brow * 128 + cOff);
        bl[i] = *(const bf16x8*)(Bs_lo + brow * 128 + cOff);
      }
      #pragma unroll
      for (int i = 0; i < 4; ++i)
        #pragma unroll
        for (int j = 0; j < 4; ++j) {
          acc[i][j] = __builtin_amdgcn_mfma_f32_16x16x32_bf16(al[i], bh[j], acc[i][j], 0, 0, 0);
          acc[i][j] = __builtin_amdgcn_mfma_f32_16x16x32_bf16(ah[i], bl[j], acc[i][j], 0, 0, 0);
          acc[i][j] = __builtin_amdgcn_mfma_f32_16x16x32_bf16(ah[i], bh[j], acc[i][j], 0, 0, 0);
        }
    }
    __syncthreads();
  }

  // --- epilogue: C/D mapping col=lane&15, row=(lane>>4)*4+reg ---
  #pragma unroll
  for (int i = 0; i < 4; ++i) {
    #pragma unroll
    for (int r = 0; r < 4; ++r) {
      int gm = rowBase + wr * 64 + i * 16 + q * 4 + r;
      if (gm < NNODES) {
        float* hp = H + (size_t)gm * 512 + colBase + wc * 64 + r2;
        #pragma unroll
        for (int j = 0; j < 4; ++j) hp[j * 16] = acc[i][j][r];
      }
    }
  }
}

// ---------------- BatchNorm ----------------

__global__ void bn_stats(const float* __restrict__ H, float* __restrict__ sums,
                         float* __restrict__ sqs) {
  int c = (blockIdx.x & 1) * 256 + threadIdx.x;
  int r0 = blockIdx.x >> 1;
  float s = 0.f, qq = 0.f;
  for (int r = r0; r < NNODES; r += 256) {
    float v = H[(size_t)r * DIM + c];
    s += v;
    qq += v * v;
  }
  atomicAdd(&sums[c], s);
  atomicAdd(&sqs[c], qq);
}

__global__ void bn_final(const float* __restrict__ sums, const float* __restrict__ sqs,
                         const float* __restrict__ gamma, const float* __restrict__ beta,
                         float* __restrict__ scale, float* __restrict__ shift) {
  int c = threadIdx.x;
  float mu  = sums[c] * (1.0f / (float)NNODES);
  float var = sqs[c] * (1.0f / (float)NNODES) - mu * mu;
  float inv = rsqrtf(var + 1e-5f);
  float sc = inv * gamma[c];
  scale[c] = sc;
  shift[c] = beta[c] - mu * sc;
}

__global__ void bn_apply(float* __restrict__ H, const float* __restrict__ X,
                         const float* __restrict__ scale, const float* __restrict__ shift) {
  const size_t total = (size_t)NNODES * (DIM / 4);
  for (size_t i = (size_t)blockIdx.x * blockDim.x + threadIdx.x; i < total;
       i += (size_t)gridDim.x * blockDim.x) {
    int c4 = ((int)(i & (DIM / 4 - 1))) * 4;
    float4 h = ((const float4*)H)[i];
    float4 xv = ((const float4*)X)[i];
    float4 r;
    r.x = fmaxf(fmaf(h.x, scale[c4 + 0], shift[c4 + 0]), 0.f) + xv.x;
    r.y = fmaxf(fmaf(h.y, scale[c4 + 1], shift[c4 + 1]), 0.f) + xv.y;
    r.z = fmaxf(fmaf(h.z, scale[c4 + 2], shift[c4 + 2]), 0.f) + xv.z;
    r.w = fmaxf(fmaf(h.w, scale[c4 + 3], shift[c4 + 3]), 0.f) + xv.w;
    ((float4*)H)[i] = r;
  }
}

// ---------------- launch ----------------

extern "C" void kernel_launch(void* const* d_in, const int* in_sizes, int n_in,
                              void* d_out, int out_size, void* d_ws, size_t ws_size,
                              hipStream_t stream) {
  (void)in_sizes; (void)n_in; (void)out_size; (void)ws_size;
  const float* x     = (const float*)d_in[0];
  const int*   ei    = (const int*)d_in[1];
  const float* Wl    = (const float*)d_in[2];
  // d_in[3] = b_l: cancels through BN mean subtraction (and is zeros) -> unused
  const float* Wr    = (const float*)d_in[4];
  const float* gamma = (const float*)d_in[5];
  const float* beta  = (const float*)d_in[6];
  float* H = (float*)d_out;

  const int* src = ei;
  const int* dst = ei + NEDGES;

  char* w = (char*)d_ws;
  float* mean_agg = (float*)w;        w += (size_t)NNODES * DIM * 4;   // 102.4 MB
  unsigned short* bhi = (unsigned short*)w;  w += (size_t)512 * 1024 * 2;  // 1 MB
  unsigned short* blo = (unsigned short*)w;  w += (size_t)512 * 1024 * 2;  // 1 MB
  int* cnt    = (int*)w;              w += (size_t)NNODES * 4;
  int* offs   = (int*)w;              w += (size_t)NNODES * 4;
  int* cursor = (int*)w;              w += (size_t)NNODES * 4;
  int* csr    = (int*)w;              w += (size_t)NEDGES * 4;
  float* sums = (float*)w;            w += (size_t)DIM * 4;
  float* sqs  = (float*)w;            w += (size_t)DIM * 4;
  float* scale= (float*)w;            w += (size_t)DIM * 4;
  float* shift= (float*)w;            w += (size_t)DIM * 4;

  hipMemsetAsync(cnt, 0, (size_t)NNODES * 4, stream);
  hipMemsetAsync(sums, 0, (size_t)2 * DIM * 4, stream);

  count_kernel<<<(NEDGES + 255) / 256, 256, 0, stream>>>(dst, cnt);
  scan_kernel<<<1, 1024, 0, stream>>>(cnt, offs, cursor);
  fill_kernel<<<(NEDGES + 255) / 256, 256, 0, stream>>>(src, dst, cursor, csr);
  convert_w_kernel<<<256, 256, 0, stream>>>(Wl, Wr, bhi, blo);
  aggregate_kernel<<<(NNODES + 3) / 4, 256, 0, stream>>>(x, offs, cnt, csr, mean_agg);
  mfma_gemm<<<dim3(4, 391), 256, 0, stream>>>(mean_agg, x, bhi, blo, H);
  bn_stats<<<512, 256, 0, stream>>>(H, sums, sqs);
  bn_final<<<1, DIM, 0, stream>>>(sums, sqs, gamma, beta, scale, shift);
  bn_apply<<<2048, 256, 0, stream>>>(H, x, scale, shift);
}

// Round 4
// 532.640 us; speedup vs baseline: 2.2359x; 1.2930x over previous
//
#include <hip/hip_runtime.h>

#define NNODES 50000
#define NEDGES 400000
#define DIM    512
#define SCAN_BLOCKS 196   // ceil(50000/256)

typedef float f32x4 __attribute__((ext_vector_type(4)));
typedef __bf16 bf16x8 __attribute__((ext_vector_type(8)));

// ---------------- helpers ----------------

// round-to-nearest-even fp32 -> bf16; bf16 bits are in [31:16] of result
__device__ __forceinline__ unsigned bf16_rne_bits(float f) {
  unsigned u = __float_as_uint(f);
  return u + 0x7FFF + ((u >> 16) & 1);
}

__device__ __forceinline__ void async16(void* lds, const void* g) {
  __builtin_amdgcn_global_load_lds(
      (const __attribute__((address_space(1))) unsigned*)g,
      (__attribute__((address_space(3))) unsigned*)lds, 16, 0, 0);
}

// ---------------- CSR build ----------------

__global__ void count_kernel(const int* __restrict__ dst, int* __restrict__ cnt) {
  int i = blockIdx.x * blockDim.x + threadIdx.x;
  if (i < NEDGES) atomicAdd(&cnt[dst[i]], 1);
}

__global__ void scan1_kernel(const int* __restrict__ cnt, int* __restrict__ part,
                             int* __restrict__ bsum) {
  __shared__ int ws4[4];
  int i = blockIdx.x * 256 + (int)threadIdx.x;
  int lane = threadIdx.x & 63, wid = threadIdx.x >> 6;
  int v = (i < NNODES) ? cnt[i] : 0;
  int s = v;
  #pragma unroll
  for (int d = 1; d < 64; d <<= 1) { int t = __shfl_up(s, d); if (lane >= d) s += t; }
  if (lane == 63) ws4[wid] = s;
  __syncthreads();
  int pre = 0;
  #pragma unroll
  for (int k = 0; k < 4; ++k) if (k < wid) pre += ws4[k];
  if (i < NNODES) part[i] = pre + s - v;       // block-local exclusive
  if (threadIdx.x == 255) bsum[blockIdx.x] = pre + s;
}

__global__ void scan2_kernel(const int* __restrict__ bsum, int* __restrict__ boff) {
  __shared__ int ws4[4];
  int lane = threadIdx.x & 63, wid = threadIdx.x >> 6;
  int i = (int)threadIdx.x;
  int v = (i < SCAN_BLOCKS) ? bsum[i] : 0;
  int s = v;
  #pragma unroll
  for (int d = 1; d < 64; d <<= 1) { int t = __shfl_up(s, d); if (lane >= d) s += t; }
  if (lane == 63) ws4[wid] = s;
  __syncthreads();
  int pre = 0;
  #pragma unroll
  for (int k = 0; k < 4; ++k) if (k < wid) pre += ws4[k];
  if (i < SCAN_BLOCKS) boff[i] = pre + s - v;  // exclusive over block sums
}

__global__ void scan3_kernel(int* __restrict__ offs, const int* __restrict__ boff,
                             int* __restrict__ cursor) {
  int i = blockIdx.x * 256 + (int)threadIdx.x;
  if (i < NNODES) {
    int o = offs[i] + boff[blockIdx.x];
    offs[i] = o;
    cursor[i] = o;
  }
}

__global__ void fill_kernel(const int* __restrict__ src, const int* __restrict__ dst,
                            int* __restrict__ cursor, int* __restrict__ csr) {
  int i = blockIdx.x * blockDim.x + threadIdx.x;
  if (i < NEDGES) {
    int d = dst[i];
    int p = atomicAdd(&cursor[d], 1);
    csr[p] = src[i];
  }
}

// ---------------- x -> bf16-hi plane (lives in d_out; dead before GEMM) ----

__global__ void convert_x_kernel(const float* __restrict__ x,
                                 unsigned short* __restrict__ xhi) {
  int t = blockIdx.x * 256 + (int)threadIdx.x;  // 3.2M threads, 8 elems each
  const float* s = x + (size_t)t * 8;
  float f[8];
  *(float4*)&f[0] = ((const float4*)s)[0];
  *(float4*)&f[4] = ((const float4*)s)[1];
  uint4 p;
  unsigned h0 = bf16_rne_bits(f[0]), h1 = bf16_rne_bits(f[1]);
  unsigned h2 = bf16_rne_bits(f[2]), h3 = bf16_rne_bits(f[3]);
  unsigned h4 = bf16_rne_bits(f[4]), h5 = bf16_rne_bits(f[5]);
  unsigned h6 = bf16_rne_bits(f[6]), h7 = bf16_rne_bits(f[7]);
  p.x = (h0 >> 16) | (h1 & 0xFFFF0000u);
  p.y = (h2 >> 16) | (h3 & 0xFFFF0000u);
  p.z = (h4 >> 16) | (h5 & 0xFFFF0000u);
  p.w = (h6 >> 16) | (h7 & 0xFFFF0000u);
  *(uint4*)(xhi + (size_t)t * 8) = p;
}

// ---------------- mean aggregation: bf16 gather -> split bf16 planes -------

__global__ void aggregate_kernel(const unsigned short* __restrict__ xhi,
                                 const int* __restrict__ offs,
                                 const int* __restrict__ cnt, const int* __restrict__ csr,
                                 unsigned short* __restrict__ ahi,
                                 unsigned short* __restrict__ alo) {
  int node = blockIdx.x * 4 + (int)(threadIdx.x >> 6);
  int lane = threadIdx.x & 63;
  if (node >= NNODES) return;
  int off = offs[node];
  int deg = cnt[node];
  float a[8] = {0.f, 0.f, 0.f, 0.f, 0.f, 0.f, 0.f, 0.f};
  for (int i = 0; i < deg; ++i) {
    int s = csr[off + i];  // wave-uniform
    uint4 v = *(const uint4*)(xhi + (size_t)s * DIM + lane * 8);
    a[0] += __uint_as_float(v.x << 16);
    a[1] += __uint_as_float(v.x & 0xFFFF0000u);
    a[2] += __uint_as_float(v.y << 16);
    a[3] += __uint_as_float(v.y & 0xFFFF0000u);
    a[4] += __uint_as_float(v.z << 16);
    a[5] += __uint_as_float(v.z & 0xFFFF0000u);
    a[6] += __uint_as_float(v.w << 16);
    a[7] += __uint_as_float(v.w & 0xFFFF0000u);
  }
  float w = 1.0f / fmaxf((float)deg, 1.0f);
  unsigned hb[8], lb[8];
  #pragma unroll
  for (int j = 0; j < 8; ++j) {
    float m = a[j] * w;
    unsigned r = bf16_rne_bits(m);
    hb[j] = r;
    lb[j] = bf16_rne_bits(m - __uint_as_float(r & 0xFFFF0000u));
  }
  uint4 ph, pl;
  ph.x = (hb[0] >> 16) | (hb[1] & 0xFFFF0000u);
  ph.y = (hb[2] >> 16) | (hb[3] & 0xFFFF0000u);
  ph.z = (hb[4] >> 16) | (hb[5] & 0xFFFF0000u);
  ph.w = (hb[6] >> 16) | (hb[7] & 0xFFFF0000u);
  pl.x = (lb[0] >> 16) | (lb[1] & 0xFFFF0000u);
  pl.y = (lb[2] >> 16) | (lb[3] & 0xFFFF0000u);
  pl.z = (lb[4] >> 16) | (lb[5] & 0xFFFF0000u);
  pl.w = (lb[6] >> 16) | (lb[7] & 0xFFFF0000u);
  *(uint4*)(ahi + (size_t)node * DIM + lane * 8) = ph;
  *(uint4*)(alo + (size_t)node * DIM + lane * 8) = pl;
}

// ---------------- W -> bf16 hi/lo, concatenated [512][1024] ----------------

__global__ void convert_w_kernel(const float* __restrict__ Wl, const float* __restrict__ Wr,
                                 unsigned short* __restrict__ bhi,
                                 unsigned short* __restrict__ blo) {
  int t = blockIdx.x * blockDim.x + threadIdx.x;
  int n  = t >> 7;
  int k  = (t & 127) * 8;
  const float* s = (k < 512) ? (Wl + (size_t)n * 512 + k)
                             : (Wr + (size_t)n * 512 + (k - 512));
  float f[8];
  *(float4*)&f[0] = ((const float4*)s)[0];
  *(float4*)&f[4] = ((const float4*)s)[1];
  unsigned hi[8], lo[8];
  #pragma unroll
  for (int i = 0; i < 8; ++i) {
    unsigned r = bf16_rne_bits(f[i]);
    hi[i] = r;
    lo[i] = bf16_rne_bits(f[i] - __uint_as_float(r & 0xFFFF0000u));
  }
  uint4 ph, pl;
  ph.x = (hi[0] >> 16) | (hi[1] & 0xFFFF0000u);
  ph.y = (hi[2] >> 16) | (hi[3] & 0xFFFF0000u);
  ph.z = (hi[4] >> 16) | (hi[5] & 0xFFFF0000u);
  ph.w = (hi[6] >> 16) | (hi[7] & 0xFFFF0000u);
  pl.x = (lo[0] >> 16) | (lo[1] & 0xFFFF0000u);
  pl.y = (lo[2] >> 16) | (lo[3] & 0xFFFF0000u);
  pl.z = (lo[4] >> 16) | (lo[5] & 0xFFFF0000u);
  pl.w = (lo[6] >> 16) | (lo[7] & 0xFFFF0000u);
  *(uint4*)(bhi + (size_t)n * 1024 + k) = ph;
  *(uint4*)(blo + (size_t)n * 1024 + k) = pl;
}

// ---------------- bf16x3 MFMA GEMM + fused BN-stats ----------------
// t<8: A = agg planes (pre-split, pure global_load_lds staging)
// t>=8: A = x fp32 (reg-load, split in VALU, swizzled ds_write)
// Grid: 1568 = 8 XCD * 196; bijective map puts a panel's 4 col-blocks on one XCD.

__launch_bounds__(256, 2)
__global__ void mfma_gemm(const unsigned short* __restrict__ AggHi,
                          const unsigned short* __restrict__ AggLo,
                          const float* __restrict__ X,
                          const unsigned short* __restrict__ Bhi,
                          const unsigned short* __restrict__ Blo,
                          float* __restrict__ H,
                          float* __restrict__ sums, float* __restrict__ sqs) {
  __shared__ char lds[65536];
  char* As_hi = lds;            // [128 rows][128 B], swizzled
  char* As_lo = lds + 16384;
  char* Bs_hi = lds + 32768;
  char* Bs_lo = lds + 49152;

  const int tid  = (int)threadIdx.x;
  const int lane = tid & 63;
  const int w    = tid >> 6;

  // XCD-aware decode: xcd = g&7, slot = g>>3, col = slot&3, panel = (slot>>2)*8+xcd
  const int g    = (int)blockIdx.x;
  const int prow = ((g >> 5) << 3) + (g & 7);   // 0..391 (391 = dummy panel)
  const int cblk = (g >> 3) & 3;
  const int colBase = cblk * 128;
  const int rowBase = prow * 128;

  const int q  = lane >> 4;
  const int r2 = lane & 15;
  const int wr = w >> 1, wc = w & 1;

  const int schunk = (((tid & 7) ^ ((tid >> 3) & 7)) << 4);  // pre-swizzled src chunk
  const int srowq  = tid >> 3;                               // 0..31

  f32x4 zero = {0.f, 0.f, 0.f, 0.f};
  f32x4 acc[4][4];
  #pragma unroll
  for (int i = 0; i < 4; ++i)
    #pragma unroll
    for (int j = 0; j < 4; ++j) acc[i][j] = zero;

  for (int t = 0; t < 16; ++t) {
    const int kk = t * 64;  // concat-K column

    // --- B: async global->LDS, source pre-swizzled ---
    #pragma unroll
    for (int c = 0; c < 4; ++c) {
      int row = c * 32 + srowq;
      const char* gh = (const char*)Bhi + (size_t)(colBase + row) * 2048 + kk * 2 + schunk;
      const char* gl = (const char*)Blo + (size_t)(colBase + row) * 2048 + kk * 2 + schunk;
      async16(Bs_hi + c * 4096 + w * 1024, gh);
      async16(Bs_lo + c * 4096 + w * 1024, gl);
    }

    if (t < 8) {
      // --- A from pre-split agg planes: pure async staging ---
      #pragma unroll
      for (int c = 0; c < 4; ++c) {
        int row = c * 32 + srowq;
        int gr = rowBase + row;
        if (gr >= NNODES) gr = NNODES - 1;
        const char* gh = (const char*)AggHi + (size_t)gr * 1024 + kk * 2 + schunk;
        const char* gl = (const char*)AggLo + (size_t)gr * 1024 + kk * 2 + schunk;
        async16(As_hi + c * 4096 + w * 1024, gh);
        async16(As_lo + c * 4096 + w * 1024, gl);
      }
    } else {
      // --- A from fp32 x: reg load + split + swizzled ds_write ---
      const int kf = kk - 512;
      float4 av[8];
      #pragma unroll
      for (int c = 0; c < 8; ++c) {
        int idx16 = c * 256 + tid;
        int row   = idx16 >> 4;
        int col16 = idx16 & 15;
        int gr = rowBase + row;
        if (gr >= NNODES) gr = NNODES - 1;
        av[c] = *(const float4*)(X + (size_t)gr * 512 + kf + col16 * 4);
      }
      #pragma unroll
      for (int c = 0; c < 8; ++c) {
        int idx16 = c * 256 + tid;
        int row   = idx16 >> 4;
        int col16 = idx16 & 15;
        int off = row * 128 + ((col16 * 8) ^ ((row & 7) << 4));
        float f0 = av[c].x, f1 = av[c].y, f2 = av[c].z, f3 = av[c].w;
        unsigned r0 = bf16_rne_bits(f0), r1 = bf16_rne_bits(f1);
        unsigned r2b = bf16_rne_bits(f2), r3 = bf16_rne_bits(f3);
        float l0 = f0 - __uint_as_float(r0 & 0xFFFF0000u);
        float l1 = f1 - __uint_as_float(r1 & 0xFFFF0000u);
        float l2 = f2 - __uint_as_float(r2b & 0xFFFF0000u);
        float l3 = f3 - __uint_as_float(r3 & 0xFFFF0000u);
        uint2 hw, lw;
        hw.x = (r0 >> 16) | (r1 & 0xFFFF0000u);
        hw.y = (r2b >> 16) | (r3 & 0xFFFF0000u);
        lw.x = (bf16_rne_bits(l0) >> 16) | (bf16_rne_bits(l1) & 0xFFFF0000u);
        lw.y = (bf16_rne_bits(l2) >> 16) | (bf16_rne_bits(l3) & 0xFFFF0000u);
        *(uint2*)(As_hi + off) = hw;
        *(uint2*)(As_lo + off) = lw;
      }
    }

    __syncthreads();

    #pragma unroll
    for (int ks = 0; ks < 2; ++ks) {
      const int cOff = (((ks * 4 + q) ^ (r2 & 7)) << 4);
      bf16x8 ah[4], al[4], bh[4], bl[4];
      #pragma unroll
      for (int i = 0; i < 4; ++i) {
        int arow = wr * 64 + i * 16 + r2;
        ah[i] = *(const bf16x8*)(As_hi + arow * 128 + cOff);
        al[i] = *(const bf16x8*)(As_lo + arow * 128 + cOff);
        int brow = wc * 64 + i * 16 + r2;
        bh[i] = *(const bf16x8*)(Bs_hi + brow * 128 + cOff);
        bl[i] = *(const bf16x8*)(Bs_lo + brow * 128 + cOff);
      }
      #pragma unroll
      for (int i = 0; i < 4; ++i)
        #pragma unroll
        for (int j = 0; j < 4; ++j) {
          acc[i][j] = __builtin_amdgcn_mfma_f32_16x16x32_bf16(al[i], bh[j], acc[i][j], 0, 0, 0);
          acc[i][j] = __builtin_amdgcn_mfma_f32_16x16x32_bf16(ah[i], bl[j], acc[i][j], 0, 0, 0);
          acc[i][j] = __builtin_amdgcn_mfma_f32_16x16x32_bf16(ah[i], bh[j], acc[i][j], 0, 0, 0);
        }
    }
    __syncthreads();
  }

  // --- epilogue: H store (C/D map col=lane&15, row=(lane>>4)*4+reg) ---
  #pragma unroll
  for (int i = 0; i < 4; ++i) {
    #pragma unroll
    for (int r = 0; r < 4; ++r) {
      int gm = rowBase + wr * 64 + i * 16 + q * 4 + r;
      if (gm < NNODES) {
        float* hp = H + (size_t)gm * 512 + colBase + wc * 64 + r2;
        #pragma unroll
        for (int j = 0; j < 4; ++j) hp[j * 16] = acc[i][j][r];
      }
    }
  }

  // --- fused BN column stats: LDS reduce then 2x128 global atomics ---
  float* lsum = (float*)lds;
  float* lsq  = (float*)(lds + 512);
  if (tid < 128) lsum[tid] = 0.f;
  else if (tid < 256) lsq[tid - 128] = 0.f;
  __syncthreads();
  #pragma unroll
  for (int j = 0; j < 4; ++j) {
    float p = 0.f, qs = 0.f;
    #pragma unroll
    for (int i = 0; i < 4; ++i)
      #pragma unroll
      for (int r = 0; r < 4; ++r) {
        int gm = rowBase + wr * 64 + i * 16 + q * 4 + r;
        if (gm < NNODES) {
          float v = acc[i][j][r];
          p += v;
          qs += v * v;
        }
      }
    int cl = wc * 64 + j * 16 + r2;
    atomicAdd(&lsum[cl], p);
    atomicAdd(&lsq[cl], qs);
  }
  __syncthreads();
  if (tid < 128) atomicAdd(&sums[colBase + tid], lsum[tid]);
  else if (tid < 256) atomicAdd(&sqs[colBase + tid - 128], lsq[tid - 128]);
}

// ---------------- BatchNorm finalize + apply ----------------

__global__ void bn_final(const float* __restrict__ sums, const float* __restrict__ sqs,
                         const float* __restrict__ gamma, const float* __restrict__ beta,
                         float* __restrict__ scale, float* __restrict__ shift) {
  int c = threadIdx.x;
  float mu  = sums[c] * (1.0f / (float)NNODES);
  float var = sqs[c] * (1.0f / (float)NNODES) - mu * mu;
  float inv = rsqrtf(var + 1e-5f);
  float sc = inv * gamma[c];
  scale[c] = sc;
  shift[c] = beta[c] - mu * sc;
}

__global__ void bn_apply(float* __restrict__ H, const float* __restrict__ X,
                         const float* __restrict__ scale, const float* __restrict__ shift) {
  const size_t total = (size_t)NNODES * (DIM / 4);
  for (size_t i = (size_t)blockIdx.x * blockDim.x + threadIdx.x; i < total;
       i += (size_t)gridDim.x * blockDim.x) {
    int c4 = ((int)(i & (DIM / 4 - 1))) * 4;
    float4 h = ((const float4*)H)[i];
    float4 xv = ((const float4*)X)[i];
    float4 r;
    r.x = fmaxf(fmaf(h.x, scale[c4 + 0], shift[c4 + 0]), 0.f) + xv.x;
    r.y = fmaxf(fmaf(h.y, scale[c4 + 1], shift[c4 + 1]), 0.f) + xv.y;
    r.z = fmaxf(fmaf(h.z, scale[c4 + 2], shift[c4 + 2]), 0.f) + xv.z;
    r.w = fmaxf(fmaf(h.w, scale[c4 + 3], shift[c4 + 3]), 0.f) + xv.w;
    ((float4*)H)[i] = r;
  }
}

// ---------------- launch ----------------

extern "C" void kernel_launch(void* const* d_in, const int* in_sizes, int n_in,
                              void* d_out, int out_size, void* d_ws, size_t ws_size,
                              hipStream_t stream) {
  (void)in_sizes; (void)n_in; (void)out_size; (void)ws_size;
  const float* x     = (const float*)d_in[0];
  const int*   ei    = (const int*)d_in[1];
  const float* Wl    = (const float*)d_in[2];
  // d_in[3] = b_l: cancels through BN mean subtraction (and is zeros) -> unused
  const float* Wr    = (const float*)d_in[4];
  const float* gamma = (const float*)d_in[5];
  const float* beta  = (const float*)d_in[6];
  float* H = (float*)d_out;

  const int* src = ei;
  const int* dst = ei + NEDGES;

  // x_hi bf16 plane borrows the first 51.2 MB of d_out (dead before GEMM writes H)
  unsigned short* xhi = (unsigned short*)d_out;

  char* w = (char*)d_ws;
  unsigned short* ahi = (unsigned short*)w;  w += (size_t)NNODES * DIM * 2;  // 51.2 MB
  unsigned short* alo = (unsigned short*)w;  w += (size_t)NNODES * DIM * 2;  // 51.2 MB
  unsigned short* bhi = (unsigned short*)w;  w += (size_t)512 * 1024 * 2;    // 1 MB
  unsigned short* blo = (unsigned short*)w;  w += (size_t)512 * 1024 * 2;    // 1 MB
  int* cnt    = (int*)w;              w += (size_t)NNODES * 4;
  int* offs   = (int*)w;              w += (size_t)NNODES * 4;
  int* cursor = (int*)w;              w += (size_t)NNODES * 4;
  int* csr    = (int*)w;              w += (size_t)NEDGES * 4;
  int* bsum   = (int*)w;              w += (size_t)256 * 4;
  int* boff   = (int*)w;              w += (size_t)256 * 4;
  float* sums = (float*)w;            w += (size_t)DIM * 4;
  float* sqs  = (float*)w;            w += (size_t)DIM * 4;
  float* scale= (float*)w;            w += (size_t)DIM * 4;
  float* shift= (float*)w;            w += (size_t)DIM * 4;

  hipMemsetAsync(cnt, 0, (size_t)NNODES * 4, stream);
  hipMemsetAsync(sums, 0, (size_t)2 * DIM * 4, stream);  // sums+sqs contiguous

  count_kernel<<<(NEDGES + 255) / 256, 256, 0, stream>>>(dst, cnt);
  scan1_kernel<<<SCAN_BLOCKS, 256, 0, stream>>>(cnt, offs, bsum);
  scan2_kernel<<<1, 256, 0, stream>>>(bsum, boff);
  scan3_kernel<<<SCAN_BLOCKS, 256, 0, stream>>>(offs, boff, cursor);
  fill_kernel<<<(NEDGES + 255) / 256, 256, 0, stream>>>(src, dst, cursor, csr);
  convert_w_kernel<<<256, 256, 0, stream>>>(Wl, Wr, bhi, blo);
  convert_x_kernel<<<(NNODES * DIM / 8 + 255) / 256, 256, 0, stream>>>(x, xhi);
  aggregate_kernel<<<(NNODES + 3) / 4, 256, 0, stream>>>(xhi, offs, cnt, csr, ahi, alo);
  mfma_gemm<<<1568, 256, 0, stream>>>(ahi, alo, x, bhi, blo, H, sums, sqs);
  bn_final<<<1, DIM, 0, stream>>>(sums, sqs, gamma, beta, scale, shift);
  bn_apply<<<2048, 256, 0, stream>>>(H, x, scale, shift);
}

// Round 5
// 431.140 us; speedup vs baseline: 2.7623x; 1.2354x over previous
//
#include <hip/hip_runtime.h>

#define NNODES 50000
#define NEDGES 400000
#define DIM    512
#define SCAN_BLOCKS 196   // ceil(50000/256)

typedef float f32x4 __attribute__((ext_vector_type(4)));
typedef _Float16 f16x8 __attribute__((ext_vector_type(8)));

// ---------------- helpers ----------------

__device__ __forceinline__ void async16(void* lds, const void* g) {
  __builtin_amdgcn_global_load_lds(
      (const __attribute__((address_space(1))) unsigned*)g,
      (__attribute__((address_space(3))) unsigned*)lds, 16, 0, 0);
}

// ---------------- CSR build ----------------

__global__ void count_kernel(const int* __restrict__ dst, int* __restrict__ cnt) {
  int i = blockIdx.x * blockDim.x + threadIdx.x;
  if (i < NEDGES) atomicAdd(&cnt[dst[i]], 1);
}

__global__ void scan1_kernel(const int* __restrict__ cnt, int* __restrict__ part,
                             int* __restrict__ bsum) {
  __shared__ int ws4[4];
  int i = blockIdx.x * 256 + (int)threadIdx.x;
  int lane = threadIdx.x & 63, wid = threadIdx.x >> 6;
  int v = (i < NNODES) ? cnt[i] : 0;
  int s = v;
  #pragma unroll
  for (int d = 1; d < 64; d <<= 1) { int t = __shfl_up(s, d); if (lane >= d) s += t; }
  if (lane == 63) ws4[wid] = s;
  __syncthreads();
  int pre = 0;
  #pragma unroll
  for (int k = 0; k < 4; ++k) if (k < wid) pre += ws4[k];
  if (i < NNODES) part[i] = pre + s - v;       // block-local exclusive
  if (threadIdx.x == 255) bsum[blockIdx.x] = pre + s;
}

__global__ void scan2_kernel(const int* __restrict__ bsum, int* __restrict__ boff) {
  __shared__ int ws4[4];
  int lane = threadIdx.x & 63, wid = threadIdx.x >> 6;
  int i = (int)threadIdx.x;
  int v = (i < SCAN_BLOCKS) ? bsum[i] : 0;
  int s = v;
  #pragma unroll
  for (int d = 1; d < 64; d <<= 1) { int t = __shfl_up(s, d); if (lane >= d) s += t; }
  if (lane == 63) ws4[wid] = s;
  __syncthreads();
  int pre = 0;
  #pragma unroll
  for (int k = 0; k < 4; ++k) if (k < wid) pre += ws4[k];
  if (i < SCAN_BLOCKS) boff[i] = pre + s - v;
}

__global__ void scan3_kernel(int* __restrict__ offs, const int* __restrict__ boff,
                             int* __restrict__ cursor) {
  int i = blockIdx.x * 256 + (int)threadIdx.x;
  if (i < NNODES) {
    int o = offs[i] + boff[blockIdx.x];
    offs[i] = o;
    cursor[i] = o;
  }
}

__global__ void fill_kernel(const int* __restrict__ src, const int* __restrict__ dst,
                            int* __restrict__ cursor, int* __restrict__ csr) {
  int i = blockIdx.x * blockDim.x + threadIdx.x;
  if (i < NEDGES) {
    int d = dst[i];
    int p = atomicAdd(&cursor[d], 1);
    csr[p] = src[i];
  }
}

// ---------------- x -> fp16 plane ----------------

__global__ void convert_x_kernel(const float* __restrict__ x, _Float16* __restrict__ xp) {
  int t = blockIdx.x * 256 + (int)threadIdx.x;  // 3.2M threads, 8 elems each
  const float4* s = (const float4*)(x + (size_t)t * 8);
  float4 f0 = s[0], f1 = s[1];
  f16x8 o;
  o[0] = (_Float16)f0.x; o[1] = (_Float16)f0.y;
  o[2] = (_Float16)f0.z; o[3] = (_Float16)f0.w;
  o[4] = (_Float16)f1.x; o[5] = (_Float16)f1.y;
  o[6] = (_Float16)f1.z; o[7] = (_Float16)f1.w;
  *(f16x8*)(xp + (size_t)t * 8) = o;
}

// ---------------- mean aggregation: fp16 gather -> fp16 plane ----------------

__global__ void aggregate_kernel(const _Float16* __restrict__ xp,
                                 const int* __restrict__ offs,
                                 const int* __restrict__ cnt, const int* __restrict__ csr,
                                 _Float16* __restrict__ agg) {
  int node = blockIdx.x * 4 + (int)(threadIdx.x >> 6);
  int lane = threadIdx.x & 63;
  if (node >= NNODES) return;
  int off = offs[node];
  int deg = cnt[node];
  float a[8] = {0.f, 0.f, 0.f, 0.f, 0.f, 0.f, 0.f, 0.f};
  for (int i = 0; i < deg; ++i) {
    int s = csr[off + i];  // wave-uniform
    f16x8 v = *(const f16x8*)(xp + (size_t)s * DIM + lane * 8);
    #pragma unroll
    for (int j = 0; j < 8; ++j) a[j] += (float)v[j];
  }
  float w = 1.0f / fmaxf((float)deg, 1.0f);
  f16x8 o;
  #pragma unroll
  for (int j = 0; j < 8; ++j) o[j] = (_Float16)(a[j] * w);
  *(f16x8*)(agg + (size_t)node * DIM + lane * 8) = o;
}

// ---------------- W -> fp16, concatenated [512][1024] ----------------
// Wc[n][k] = (k<512 ? Wl[n][k] : Wr[n][k-512])

__global__ void convert_w_kernel(const float* __restrict__ Wl, const float* __restrict__ Wr,
                                 _Float16* __restrict__ Wc) {
  int t = blockIdx.x * blockDim.x + threadIdx.x;  // 65536 threads
  int n  = t >> 7;
  int k  = (t & 127) * 8;
  const float* s = (k < 512) ? (Wl + (size_t)n * 512 + k)
                             : (Wr + (size_t)n * 512 + (k - 512));
  float f[8];
  *(float4*)&f[0] = ((const float4*)s)[0];
  *(float4*)&f[4] = ((const float4*)s)[1];
  f16x8 o;
  #pragma unroll
  for (int i = 0; i < 8; ++i) o[i] = (_Float16)f[i];
  *(f16x8*)(Wc + (size_t)n * 1024 + k) = o;
}

// ---------------- fp16 MFMA GEMM + fused BN-stats ----------------
// H[m][n] = sum_k Acat[m][k] * Wc[n][k]; Acat = [agg | xp] fp16 planes.
// 128x128 tile, BK=64, 4 waves (2x2 of 64x64), 16x16x32 f16 MFMA.
// All staging via global_load_lds with pre-swizzled source (linear LDS dest,
// XOR-swizzled read — involution verified in R3/R4, 0 bank conflicts).
// Grid: 1568 = 8 XCD * 196; bijective map puts a panel's 4 col-blocks on one XCD.

__launch_bounds__(256, 4)
__global__ void mfma_gemm(const _Float16* __restrict__ Agg,
                          const _Float16* __restrict__ Xp,
                          const _Float16* __restrict__ Wc,
                          float* __restrict__ H,
                          float* __restrict__ sums, float* __restrict__ sqs) {
  __shared__ char lds[32768];
  char* As = lds;            // [128 rows][128 B], swizzled
  char* Bs = lds + 16384;

  const int tid  = (int)threadIdx.x;
  const int lane = tid & 63;
  const int w    = tid >> 6;

  // XCD-aware decode: xcd = g&7, col = (g>>3)&3, panel = (g>>5)*8 + (g&7)
  const int g    = (int)blockIdx.x;
  const int prow = ((g >> 5) << 3) + (g & 7);   // 0..391 (391 = dummy panel)
  const int cblk = (g >> 3) & 3;
  const int colBase = cblk * 128;
  const int rowBase = prow * 128;

  const int q  = lane >> 4;
  const int r2 = lane & 15;
  const int wr = w >> 1, wc = w & 1;

  const int schunk = (((tid & 7) ^ ((tid >> 3) & 7)) << 4);  // pre-swizzled src chunk
  const int srowq  = tid >> 3;                               // 0..31

  f32x4 zero = {0.f, 0.f, 0.f, 0.f};
  f32x4 acc[4][4];
  #pragma unroll
  for (int i = 0; i < 4; ++i)
    #pragma unroll
    for (int j = 0; j < 4; ++j) acc[i][j] = zero;

  for (int t = 0; t < 16; ++t) {
    // A plane: agg for t<8, x for t>=8; byte col within 1024-B row
    const _Float16* Ap = (t < 8) ? Agg : Xp;
    const int kbA = (t & 7) * 128;   // bytes
    const int kbB = t * 128;         // bytes within 2048-B Wc row

    #pragma unroll
    for (int c = 0; c < 4; ++c) {
      int row = c * 32 + srowq;
      const char* gb = (const char*)Wc + (size_t)(colBase + row) * 2048 + kbB + schunk;
      async16(Bs + c * 4096 + w * 1024, gb);
      int gr = rowBase + row;
      if (gr >= NNODES) gr = NNODES - 1;
      const char* ga = (const char*)Ap + (size_t)gr * 1024 + kbA + schunk;
      async16(As + c * 4096 + w * 1024, ga);
    }

    __syncthreads();

    #pragma unroll
    for (int ks = 0; ks < 2; ++ks) {
      const int cOff = (((ks * 4 + q) ^ (r2 & 7)) << 4);
      f16x8 a[4], b[4];
      #pragma unroll
      for (int i = 0; i < 4; ++i) {
        int arow = wr * 64 + i * 16 + r2;
        a[i] = *(const f16x8*)(As + arow * 128 + cOff);
        int brow = wc * 64 + i * 16 + r2;
        b[i] = *(const f16x8*)(Bs + brow * 128 + cOff);
      }
      #pragma unroll
      for (int i = 0; i < 4; ++i)
        #pragma unroll
        for (int j = 0; j < 4; ++j)
          acc[i][j] = __builtin_amdgcn_mfma_f32_16x16x32_f16(a[i], b[j], acc[i][j], 0, 0, 0);
    }
    __syncthreads();
  }

  // --- epilogue: H store (C/D map col=lane&15, row=(lane>>4)*4+reg) ---
  #pragma unroll
  for (int i = 0; i < 4; ++i) {
    #pragma unroll
    for (int r = 0; r < 4; ++r) {
      int gm = rowBase + wr * 64 + i * 16 + q * 4 + r;
      if (gm < NNODES) {
        float* hp = H + (size_t)gm * 512 + colBase + wc * 64 + r2;
        #pragma unroll
        for (int j = 0; j < 4; ++j) hp[j * 16] = acc[i][j][r];
      }
    }
  }

  // --- fused BN column stats: LDS reduce then 2x128 global atomics ---
  float* lsum = (float*)lds;
  float* lsq  = (float*)(lds + 512);
  if (tid < 128) lsum[tid] = 0.f;
  else if (tid < 256) lsq[tid - 128] = 0.f;
  __syncthreads();
  #pragma unroll
  for (int j = 0; j < 4; ++j) {
    float p = 0.f, qs = 0.f;
    #pragma unroll
    for (int i = 0; i < 4; ++i)
      #pragma unroll
      for (int r = 0; r < 4; ++r) {
        int gm = rowBase + wr * 64 + i * 16 + q * 4 + r;
        if (gm < NNODES) {
          float v = acc[i][j][r];
          p += v;
          qs += v * v;
        }
      }
    int cl = wc * 64 + j * 16 + r2;
    atomicAdd(&lsum[cl], p);
    atomicAdd(&lsq[cl], qs);
  }
  __syncthreads();
  if (tid < 128) atomicAdd(&sums[colBase + tid], lsum[tid]);
  else if (tid < 256) atomicAdd(&sqs[colBase + tid - 128], lsq[tid - 128]);
}

// ---------------- BatchNorm finalize + apply ----------------

__global__ void bn_final(const float* __restrict__ sums, const float* __restrict__ sqs,
                         const float* __restrict__ gamma, const float* __restrict__ beta,
                         float* __restrict__ scale, float* __restrict__ shift) {
  int c = threadIdx.x;
  float mu  = sums[c] * (1.0f / (float)NNODES);
  float var = sqs[c] * (1.0f / (float)NNODES) - mu * mu;
  float inv = rsqrtf(var + 1e-5f);
  float sc = inv * gamma[c];
  scale[c] = sc;
  shift[c] = beta[c] - mu * sc;
}

__global__ void bn_apply(float* __restrict__ H, const float* __restrict__ X,
                         const float* __restrict__ scale, const float* __restrict__ shift) {
  const size_t total = (size_t)NNODES * (DIM / 4);
  for (size_t i = (size_t)blockIdx.x * blockDim.x + threadIdx.x; i < total;
       i += (size_t)gridDim.x * blockDim.x) {
    int c4 = ((int)(i & (DIM / 4 - 1))) * 4;
    float4 h = ((const float4*)H)[i];
    float4 xv = ((const float4*)X)[i];
    float4 r;
    r.x = fmaxf(fmaf(h.x, scale[c4 + 0], shift[c4 + 0]), 0.f) + xv.x;
    r.y = fmaxf(fmaf(h.y, scale[c4 + 1], shift[c4 + 1]), 0.f) + xv.y;
    r.z = fmaxf(fmaf(h.z, scale[c4 + 2], shift[c4 + 2]), 0.f) + xv.z;
    r.w = fmaxf(fmaf(h.w, scale[c4 + 3], shift[c4 + 3]), 0.f) + xv.w;
    ((float4*)H)[i] = r;
  }
}

// ---------------- launch ----------------

extern "C" void kernel_launch(void* const* d_in, const int* in_sizes, int n_in,
                              void* d_out, int out_size, void* d_ws, size_t ws_size,
                              hipStream_t stream) {
  (void)in_sizes; (void)n_in; (void)out_size; (void)ws_size;
  const float* x     = (const float*)d_in[0];
  const int*   ei    = (const int*)d_in[1];
  const float* Wl    = (const float*)d_in[2];
  // d_in[3] = b_l: cancels through BN mean subtraction (and is zeros) -> unused
  const float* Wr    = (const float*)d_in[4];
  const float* gamma = (const float*)d_in[5];
  const float* beta  = (const float*)d_in[6];
  float* H = (float*)d_out;

  const int* src = ei;
  const int* dst = ei + NEDGES;

  char* w = (char*)d_ws;
  _Float16* xp  = (_Float16*)w;  w += (size_t)NNODES * DIM * 2;  // 51.2 MB
  _Float16* agg = (_Float16*)w;  w += (size_t)NNODES * DIM * 2;  // 51.2 MB
  _Float16* wcc = (_Float16*)w;  w += (size_t)512 * 1024 * 2;    // 1 MB
  int* cnt    = (int*)w;         w += (size_t)NNODES * 4;
  int* offs   = (int*)w;         w += (size_t)NNODES * 4;
  int* cursor = (int*)w;         w += (size_t)NNODES * 4;
  int* csr    = (int*)w;         w += (size_t)NEDGES * 4;
  int* bsum   = (int*)w;         w += (size_t)256 * 4;
  int* boff   = (int*)w;         w += (size_t)256 * 4;
  float* sums = (float*)w;       w += (size_t)DIM * 4;
  float* sqs  = (float*)w;       w += (size_t)DIM * 4;
  float* scale= (float*)w;       w += (size_t)DIM * 4;
  float* shift= (float*)w;       w += (size_t)DIM * 4;

  hipMemsetAsync(cnt, 0, (size_t)NNODES * 4, stream);
  hipMemsetAsync(sums, 0, (size_t)2 * DIM * 4, stream);  // sums+sqs contiguous

  count_kernel<<<(NEDGES + 255) / 256, 256, 0, stream>>>(dst, cnt);
  scan1_kernel<<<SCAN_BLOCKS, 256, 0, stream>>>(cnt, offs, bsum);
  scan2_kernel<<<1, 256, 0, stream>>>(bsum, boff);
  scan3_kernel<<<SCAN_BLOCKS, 256, 0, stream>>>(offs, boff, cursor);
  fill_kernel<<<(NEDGES + 255) / 256, 256, 0, stream>>>(src, dst, cursor, csr);
  convert_w_kernel<<<256, 256, 0, stream>>>(Wl, Wr, wcc);
  convert_x_kernel<<<(NNODES * DIM / 8 + 255) / 256, 256, 0, stream>>>(x, xp);
  aggregate_kernel<<<(NNODES + 3) / 4, 256, 0, stream>>>(xp, offs, cnt, csr, agg);
  mfma_gemm<<<1568, 256, 0, stream>>>(agg, xp, wcc, H, sums, sqs);
  bn_final<<<1, DIM, 0, stream>>>(sums, sqs, gamma, beta, scale, shift);
  bn_apply<<<2048, 256, 0, stream>>>(H, x, scale, shift);
}